// Round 10
// baseline (243.745 us; speedup 1.0000x reference)
//
#include <hip/hip_runtime.h>
#include <math.h>

#define NROW 8192
#define DDIM 256
#define BM 128
#define BN 64           // column-half blocks: wave tile 64x32 -> 32 acc regs
#define NT_SYM 2080     // 64*65/2 lower-triangular 128x128 logical tiles
#define NT_FULL 4096
#define NT_TOTAL (2 * NT_SYM + NT_FULL)   // 8256 logical tiles
#define GRID (2 * NT_TOTAL)               // 2 column-halves each = 16512

typedef __attribute__((ext_vector_type(16))) float f32x16;
typedef __attribute__((ext_vector_type(4)))  int   i32x4;
typedef __attribute__((ext_vector_type(8)))  int   i32x8;

// DPP row_ror butterfly add: after ror 1,2,4,8 every lane of each 16-lane row
// holds the row sum. VALU pipe only — no DS traffic.
template <int CTRL>
static __device__ inline float dpp_ror_add(float v) {
    int s = __float_as_int(v);
    int r = __builtin_amdgcn_update_dpp(0, s, CTRL, 0xF, 0xF, true);
    return v + __int_as_float(r);
}
static __device__ inline float row16_sum(float v) {
    v = dpp_ror_add<0x121>(v);
    v = dpp_ror_add<0x122>(v);
    v = dpp_ror_add<0x124>(v);
    v = dpp_ror_add<0x128>(v);
    return v;
}

// Pack 4 floats -> 4 fp8 e4m3 bytes (HW cvt, OCP on gfx950 — self-consistent
// with the fp8 MFMA's decode).
static __device__ inline unsigned int pack_fp8x4(float a, float b, float c, float d) {
    int p = __builtin_amdgcn_cvt_pk_fp8_f32(a, b, 0, false);
    p = __builtin_amdgcn_cvt_pk_fp8_f32(c, d, p, true);
    return (unsigned int)p;
}

// One wave per row: L2-normalize H1/H2 rows, scale by sqrt(2*log2(e)) so the
// fp8 Gram entries come out as 2*log2(e)*s -> exp(2s) == exp2(acc).
// diag[row] = 2*dot(z1n,z2n) fp32 (exact). Zero-inits rowsums and out.
__global__ __launch_bounds__(256) void normalize_kernel(
        const float* __restrict__ h1, const float* __restrict__ h2,
        unsigned char* __restrict__ z1b, unsigned char* __restrict__ z2b,
        float* __restrict__ diag,
        float* __restrict__ rs1, float* __restrict__ rs2,
        float* __restrict__ rbr, float* __restrict__ rbc,
        float* __restrict__ out) {
    int wave = threadIdx.x >> 6;
    int lane = threadIdx.x & 63;
    int row  = blockIdx.x * 4 + wave;
    if (blockIdx.x == 0 && threadIdx.x == 0) out[0] = 0.f;
    const float4* p1 = (const float4*)(h1 + (size_t)row * DDIM);
    const float4* p2 = (const float4*)(h2 + (size_t)row * DDIM);
    float4 a = p1[lane];
    float4 b = p2[lane];
    float s1 = a.x*a.x + a.y*a.y + a.z*a.z + a.w*a.w;
    float s2 = b.x*b.x + b.y*b.y + b.z*b.z + b.w*b.w;
    #pragma unroll
    for (int m = 1; m < 64; m <<= 1) { s1 += __shfl_xor(s1, m); s2 += __shfl_xor(s2, m); }
    float r1 = 1.0f / fmaxf(sqrtf(s1), 1e-12f);
    float r2 = 1.0f / fmaxf(sqrtf(s2), 1e-12f);
    float n1x = a.x*r1, n1y = a.y*r1, n1z = a.z*r1, n1w = a.w*r1;
    float n2x = b.x*r2, n2y = b.y*r2, n2z = b.z*r2, n2w = b.w*r2;
    float dt = n1x*n2x + n1y*n2y + n1z*n2z + n1w*n2w;
    #pragma unroll
    for (int m = 1; m < 64; m <<= 1) dt += __shfl_xor(dt, m);
    if (lane == 0) {
        diag[row] = 2.0f * dt;
        rs1[row] = 0.f; rs2[row] = 0.f; rbr[row] = 0.f; rbc[row] = 0.f;
    }
    const float SC = 1.69864364f;   // sqrt(2 * log2(e))
    ((unsigned int*)(z1b + (size_t)row * DDIM))[lane] =
        pack_fp8x4(n1x*SC, n1y*SC, n1z*SC, n1w*SC);
    ((unsigned int*)(z2b + (size_t)row * DDIM))[lane] =
        pack_fp8x4(n2x*SC, n2y*SC, n2z*SC, n2w*SC);
}

// R13: ZERO main-loop barriers. Ledger: 5 structural shaves (VALU movs, DS
// shuffles, B-LDS, +occupancy, -46% fabric traffic) all null-or-negative;
// no pipe >50%. Remaining untested mechanism: the 2 barrier+vmcnt(0) drains
// per block serialize all resident waves against full memory latency (the
// guide's m97 barrier-drain stall, in miniature). Fix: A fragments load
// DIRECTLY from global like B (identical per-lane 32B gather; byte-identical
// to what the swizzled-LDS path delivered: row*256 + kt*128 + ks*64 + kh*32).
// No global_load_lds, no LDS tile, no __syncthreads until the epilogue
// scratch combine. 24 independent dwordx4 gathers + 8 MFMAs per wave,
// compiler-scheduled. A fetched 2x per block (wc-pair) — L1/L2 absorbs;
// R12 proved traffic isn't the limit. XCD swizzle reverted (R12: -9%,
// concurrent same-panel atomics + occupancy dip).
__global__ __launch_bounds__(256, 6) void expsum_kernel(
        const unsigned char* __restrict__ z1, const unsigned char* __restrict__ z2,
        float* __restrict__ rs1, float* __restrict__ rs2,
        float* __restrict__ rbr, float* __restrict__ rbc) {
    int t  = blockIdx.x >> 1;
    int ch = blockIdx.x & 1;           // which 64-col half of the 128x128 tile
    int kind, tt;
    if (t < NT_SYM)            { kind = 0; tt = t; }
    else if (t < 2 * NT_SYM)   { kind = 1; tt = t - NT_SYM; }
    else                       { kind = 2; tt = t - 2 * NT_SYM; }

    int by, bx;
    const unsigned char *Ap, *Bp;
    float *rowsum, *colsum;
    if (kind == 2) {
        by = tt >> 6; bx = tt & 63;
        Ap = z1; Bp = z2; rowsum = rbr; colsum = rbc;
    } else {
        by = (int)((sqrtf(8.0f * (float)tt + 1.0f) - 1.0f) * 0.5f);
        while ((by + 1) * (by + 2) / 2 <= tt) ++by;
        while (by * (by + 1) / 2 > tt) --by;
        bx = tt - by * (by + 1) / 2;          // bx <= by
        const unsigned char* z = (kind == 0) ? z1 : z2;
        Ap = z; Bp = z;
        rowsum = (kind == 0) ? rs1 : rs2;
        colsum = (bx == by) ? nullptr : rowsum;
    }

    const int rt = by * BM;
    const int ct = bx * BM + ch * BN;    // global col base of this half

    __shared__ float lds_rp[2][2][BM];                   // [wc][colhalf][row] 2 KB
    __shared__ float lds_cp[2][2][BN];                   // [wr][kh][col]      1 KB

    const int tid  = threadIdx.x;
    const int lane = tid & 63;
    const int wid  = tid >> 6;
    const int wr   = wid & 1;            // 64-row half
    const int wc   = wid >> 1;           // 32-col quarter (of the 64-col tile)
    const int l31  = lane & 31;
    const int kh   = lane >> 5;          // k-half of the 64-wide k-step

    // Per-lane operand bases: fragment row in lane&31, k-bytes kh*32 + imm.
    const unsigned char* gA0 =
        Ap + (size_t)(rt + wr * 64 + l31) * DDIM + kh * 32;
    const unsigned char* gA1 = gA0 + 32 * DDIM;
    const unsigned char* gB  =
        Bp + (size_t)(ct + wc * 32 + l31) * DDIM + kh * 32;

    f32x16 acc0, acc1;
    #pragma unroll
    for (int r = 0; r < 16; ++r) { acc0[r] = 0.f; acc1[r] = 0.f; }

    #pragma unroll
    for (int kt = 0; kt < 2; ++kt) {
        #pragma unroll
        for (int ks = 0; ks < 2; ++ks) {        // K=64 per step, 4 steps total
            const int o = kt * 128 + ks * 64;
            i32x8 a0, a1, bv;
            *((i32x4*)&a0)     = *(const i32x4*)(gA0 + o);
            *((i32x4*)&a0 + 1) = *(const i32x4*)(gA0 + o + 16);
            *((i32x4*)&a1)     = *(const i32x4*)(gA1 + o);
            *((i32x4*)&a1 + 1) = *(const i32x4*)(gA1 + o + 16);
            *((i32x4*)&bv)     = *(const i32x4*)(gB + o);
            *((i32x4*)&bv + 1) = *(const i32x4*)(gB + o + 16);
            acc0 = __builtin_amdgcn_mfma_scale_f32_32x32x64_f8f6f4(
                a0, bv, acc0, 0, 0, 0, 0x7F7F7F7F, 0, 0x7F7F7F7F);
            acc1 = __builtin_amdgcn_mfma_scale_f32_32x32x64_f8f6f4(
                a1, bv, acc1, 0, 0, 0, 0x7F7F7F7F, 0, 0x7F7F7F7F);
        }
    }

    // C/D layout (32x32): col = lane&31, row = (reg&3) + 8*(reg>>2) + 4*kh.
    // acc = 2*log2e*s -> raw v_exp_f32 (inputs bounded ~|2.9|).
    // No shuffles: after row16_sum each 16-lane group's lane 0 (lanes
    // 0/16/32/48) holds a 16-col x kh-half partial -> write to its own
    // [wc][colhalf] scratch plane. Col partials: every lane writes its
    // [wr][kh] plane. Final pass sums 4 planes -> ONE atomic per row/col.
    float cp0 = 0.f, cp1 = 0.f;
    #pragma unroll
    for (int r = 0; r < 16; ++r) {
        float e0 = __builtin_amdgcn_exp2f(acc0[r]);
        float e1 = __builtin_amdgcn_exp2f(acc1[r]);
        cp0 += e0;
        cp1 += e1;
        float v0 = row16_sum(e0);
        float v1 = row16_sum(e1);
        if ((lane & 15) == 0) {          // lanes 0,16,32,48
            int rloc = wr * 64 + 4 * kh + (r & 3) + 8 * (r >> 2);
            int colhalf = l31 >> 4;      // 0 for lanes 0/32, 1 for 16/48
            lds_rp[wc][colhalf][rloc]      = v0;
            lds_rp[wc][colhalf][rloc + 32] = v1;
        }
    }
    lds_cp[wr][kh][wc * 32 + l31] = cp0 + cp1;
    __syncthreads();
    if (tid < BM) {
        float s = lds_rp[0][0][tid] + lds_rp[0][1][tid]
                + lds_rp[1][0][tid] + lds_rp[1][1][tid];
        atomicAdd(&rowsum[rt + tid], s);
    } else if (colsum && tid < BM + BN) {
        int c = tid - BM;
        float s = lds_cp[0][0][c] + lds_cp[0][1][c]
                + lds_cp[1][0][c] + lds_cp[1][1][c];
        atomicAdd(&colsum[ct + c], s);
    }
}

// 32 blocks x 256 threads, one row each; block-reduce then one atomicAdd.
__global__ __launch_bounds__(256) void finalize_kernel(
        const float* __restrict__ rs1, const float* __restrict__ rs2,
        const float* __restrict__ rbr, const float* __restrict__ rbc,
        const float* __restrict__ diag, float* __restrict__ out) {
    __shared__ float s4[4];
    const float E2 = 7.38905609893065f;   // exp(1/tau), tau=0.5
    int i = blockIdx.x * 256 + threadIdx.x;
    float den1 = rs1[i] + rbr[i] - E2;
    float den2 = rs2[i] + rbc[i] - E2;
    float v = 0.5f * (logf(den1) + logf(den2)) - diag[i];
    #pragma unroll
    for (int m = 1; m < 64; m <<= 1) v += __shfl_xor(v, m);
    if ((threadIdx.x & 63) == 0) s4[threadIdx.x >> 6] = v;
    __syncthreads();
    if (threadIdx.x == 0) {
        float t = (s4[0] + s4[1] + s4[2] + s4[3]) * (1.0f / (float)NROW);
        atomicAdd(out, t);
    }
}

extern "C" void kernel_launch(void* const* d_in, const int* in_sizes, int n_in,
                              void* d_out, int out_size, void* d_ws, size_t ws_size,
                              hipStream_t stream) {
    const float* h1 = (const float*)d_in[0];
    const float* h2 = (const float*)d_in[1];
    float* out = (float*)d_out;

    char* ws = (char*)d_ws;
    unsigned char* z1b = (unsigned char*)ws;                             // 2 MB
    unsigned char* z2b = (unsigned char*)(ws + (size_t)NROW * DDIM);     // 2 MB
    float* sums = (float*)(ws + (size_t)2 * NROW * DDIM);
    float* rs1  = sums;
    float* rs2  = sums + NROW;
    float* rbr  = sums + 2 * NROW;
    float* rbc  = sums + 3 * NROW;
    float* diag = sums + 4 * NROW;

    normalize_kernel<<<NROW / 4, 256, 0, stream>>>(h1, h2, z1b, z2b, diag,
                                                   rs1, rs2, rbr, rbc, out);

    expsum_kernel<<<GRID, 256, 0, stream>>>(z1b, z2b, rs1, rs2, rbr, rbc);

    finalize_kernel<<<NROW / 256, 256, 0, stream>>>(rs1, rs2, rbr, rbc, diag, out);
}